// Round 3
// baseline (86.104 us; speedup 1.0000x reference)
//
#include <hip/hip_runtime.h>

// PointWarping2 = flash-attention with head-dim 3:
//   flow2 = softmax(-d2/s^2) @ f1  (Schraudolph exp2, MAGIC-fold).
// R20: FUSE pack+main into ONE kernel (no workspace use at all).
// Rationale: R19 showed main is not dependency-bound; in-kernel physics
// says ~5us busy, yet residual is ~25us -> suspect inter-kernel overhead
// (pack node + graph boundary + ws round-trip + fill->pack serialization).
// Score MFMA moves to f16 (mfma_f32_32x32x16_f16) so per-source A-frags
// are buildable on the fly in ~21 VALU (1-op RNE cvts, no bf16 3-op rne).
// PV operands (cross-lane flow values) exchange via 256B wave-private
// double-buffered LDS (4 ds_write_b16 + 2 ds_read_b128/tile, no barriers).
//
// Score MFMA: D[src][q] = A.B + 0, K=16:
//   A k0-7  (lanes<32, per source): {yx,yx, yy,yy, yz,yz, wh,wl}
//     (w = -c1*|y|^2 fp32 -> f16 hi/lo)
//   A k8-15 (lanes>=32): {1,1,1,0,0,0,0,0} constant
//   B k0-7  (per query): {Xh,Xl, Yh,Yl, Zh,Zl, 1,1}   (X = 2*c1*qx hi/lo)
//   B k8-15: {qch,qcl, MAGH, 0,...}  (MAGH = f16(49152) exact)
//   => D = MAGIC - c1*d2 exactly as R12's arg.
// PV: D-layout (col=lane&31=q, row=(reg&3)+8*(reg>>2)+4*hi=src) means
// cvt_pkrtz(w[2j],w[2j+1]) IS the PV B-operand when the A-side (flow vals)
// is stored in the matching permuted order {0-3,8-11 | 4-7,12-15} per
// 16-source group -- which the LDS write-position math implements.

#define N1S  8192
#define N2S  8192
#define BATCH 2
#define NQ   (BATCH * N2S)       // 16384 queries
#define BLK  512                 // 8 waves; each wave: 1024 sources = 32 tiles
#define LOG2E 1.4426950408889634f
#define MAGIC 49152.0f           // 1.5*2^15
#define CLAMPS (MAGIC - 120.0f)
#define KBITS 1064990910         // (127<<23) - 362306: rel err +-3.04%
#define ONEH 0x3C00u             // f16(1.0)
#define MAGH 0x7A00u             // f16(49152.0), exact

typedef __attribute__((ext_vector_type(8)))  _Float16 f16x8;
typedef __attribute__((ext_vector_type(2)))  _Float16 f16x2;
typedef __attribute__((ext_vector_type(16))) float    f32x16;

__device__ __forceinline__ float read_scale(const void* p) {
    // resol_factor: 1-elem array; Python int -> int32, float -> fp32.
    int iv = *(const int*)p;
    if (iv > -(1 << 23) && iv < (1 << 23)) return (float)iv;
    return *(const float*)p;
}

__device__ __forceinline__ unsigned hb(float v) {        // f16 bits, RNE
    return (unsigned)__builtin_bit_cast(unsigned short, (_Float16)v);
}
__device__ __forceinline__ float h2f(unsigned b16) {     // f16 bits -> fp32
    return (float)__builtin_bit_cast(_Float16, (unsigned short)(b16 & 0xFFFFu));
}
__device__ __forceinline__ unsigned pkrtz(float a, float b) { // {f16(a),f16(b)}
    return __builtin_bit_cast(unsigned, __builtin_amdgcn_cvt_pkrtz(a, b));
}

__global__ __launch_bounds__(BLK, 4) void pw2_fused(
    const float* __restrict__ xyz1, const float* __restrict__ xyz2,
    const float* __restrict__ flow1, const void* __restrict__ resol,
    float* __restrict__ out)
{
    // lf: [wave8][buf2][g2][h2][c4][pos8] f16 -> 256 elems (512B) per wave
    __shared__ unsigned short lf[8 * 256];
    __shared__ float4 red[8][32];     // [wave][query] partial (nx,ny,nz,den)

    const int t  = threadIdx.x;
    const int w  = t >> 6, l = t & 63, lq = l & 31, hi = l >> 5;
    const int qblk  = blockIdx.x * 32;
    const int b     = qblk >> 13;
    const int nbase = qblk & (N2S - 1);

    const float scale = read_scale(resol);
    const float c1 = LOG2E / (scale * scale), twoC = 2.0f * c1;
    const float* x2b = xyz2 + b * 3 * N2S;

    // ---- per-lane query constants -> score B fragment (col = lq) ----
    const int n = nbase + lq;
    const float qx = x2b[0*N2S+n], qy = x2b[1*N2S+n], qz = x2b[2*N2S+n];
    const float Xc = twoC*qx, Yc = twoC*qy, Zc = twoC*qz;
    const unsigned Xh = hb(Xc), Yh = hb(Yc), Zh = hb(Zc);
    const unsigned Xl = hb(Xc - h2f(Xh));
    const unsigned Yl = hb(Yc - h2f(Yh));
    const unsigned Zl = hb(Zc - h2f(Zh));
    const float qc = -c1 * (qx*qx + qy*qy + qz*qz);
    const unsigned Qh = hb(qc), Ql = hb(qc - h2f(Qh));
    uint4 bw;
    bw.x = hi ? (Qh | (Ql << 16)) : (Xh | (Xl << 16));
    bw.y = hi ? MAGH              : (Yh | (Yl << 16));
    bw.z = hi ? 0u                : (Zh | (Zl << 16));
    bw.w = hi ? 0u                : (ONEH | (ONEH << 16));
    const f16x8 Bf = __builtin_bit_cast(f16x8, bw);

    f32x16 acc, zc;
#pragma unroll
    for (int k = 0; k < 16; ++k) { acc[k] = 0.f; zc[k] = 0.f; }

    const float* x1b = xyz1  + b * 3 * N1S;
    const float* f1b = flow1 + b * 3 * N1S;
    const int wbase = w * 1024;

    // LDS element indices (x2 bytes). write: this lane's source position in
    // the permuted record stream; read: record (g, h=hi, c=l&3).
    const int jj = lq & 15, gg = lq >> 4;
    const int hp  = (jj >> 2) & 1;
    const int pos = (jj & 3) | ((jj >> 3) << 2);
    const int ew = w*256 + gg*64 + hp*32 + pos;   // + buf*128 + c*8
    const int er = w*256 + hi*32 + (l & 3)*8;     // + buf*128 + g*64

    float rx, ry, rz, fx, fy, fz;

#define LOADR(S) do {                                                         \
    int sc = (S); sc = sc < N1S ? sc : N1S - 1;   /* batch-local clamp */     \
    rx = x1b[sc]; ry = x1b[N1S+sc]; rz = x1b[2*N1S+sc];                       \
    fx = f1b[sc]; fy = f1b[N1S+sc]; fz = f1b[2*N1S+sc];                       \
} while (0)

#define MAKEA(AW, HFX, HFY, HFZ) do {                                         \
    const float yx = rx+fx, yy = ry+fy, yz = rz+fz;                           \
    const float wv = -c1 * (yx*yx + yy*yy + yz*yz);                           \
    const unsigned hx = hb(yx), hy = hb(yy), hz = hb(yz);                     \
    const unsigned wh = hb(wv), wl2 = hb(wv - h2f(wh));                       \
    (AW).x = hi ? (ONEH | (ONEH << 16)) : (hx | (hx << 16));                  \
    (AW).y = hi ? ONEH : (hy | (hy << 16));                                   \
    (AW).z = hi ? 0u : (hz | (hz << 16));                                     \
    (AW).w = hi ? 0u : (wh | (wl2 << 16));                                    \
    (HFX) = hb(fx); (HFY) = hb(fy); (HFZ) = hb(fz);                           \
} while (0)

#define FWRITE(BUF, HFX, HFY, HFZ) do { if (hi == 0) {                        \
    const int a0 = ew + (BUF)*128;                                            \
    lf[a0]      = (unsigned short)(HFX);                                      \
    lf[a0 + 8]  = (unsigned short)(HFY);                                      \
    lf[a0 + 16] = (unsigned short)(HFZ);                                      \
    lf[a0 + 24] = (unsigned short)ONEH; } } while (0)

#define EXPPV(BUF) do {                                                       \
    const int rb = er + (BUF)*128;                                            \
    const f16x8 F0 = *(const f16x8*)&lf[rb];                                  \
    const f16x8 F1 = *(const f16x8*)&lf[rb + 64];                             \
    uint4 p;                                                                  \
    {                                                                         \
        float s0 = fmaxf(d[0], CLAMPS), s1 = fmaxf(d[1], CLAMPS);             \
        float s2 = fmaxf(d[2], CLAMPS), s3 = fmaxf(d[3], CLAMPS);             \
        float s4 = fmaxf(d[4], CLAMPS), s5 = fmaxf(d[5], CLAMPS);             \
        float w0 = __builtin_bit_cast(float,(__builtin_bit_cast(int,s0)<<15)+KBITS);\
        float w1 = __builtin_bit_cast(float,(__builtin_bit_cast(int,s1)<<15)+KBITS);\
        float w2 = __builtin_bit_cast(float,(__builtin_bit_cast(int,s2)<<15)+KBITS);\
        float w3 = __builtin_bit_cast(float,(__builtin_bit_cast(int,s3)<<15)+KBITS);\
        float w4 = __builtin_bit_cast(float,(__builtin_bit_cast(int,s4)<<15)+KBITS);\
        float w5 = __builtin_bit_cast(float,(__builtin_bit_cast(int,s5)<<15)+KBITS);\
        float s6 = fmaxf(d[6], CLAMPS), s7 = fmaxf(d[7], CLAMPS);             \
        float w6 = __builtin_bit_cast(float,(__builtin_bit_cast(int,s6)<<15)+KBITS);\
        float w7 = __builtin_bit_cast(float,(__builtin_bit_cast(int,s7)<<15)+KBITS);\
        p.x = pkrtz(w0, w1); p.y = pkrtz(w2, w3);                             \
        p.z = pkrtz(w4, w5); p.w = pkrtz(w6, w7);                             \
    }                                                                         \
    acc = __builtin_amdgcn_mfma_f32_32x32x16_f16(                             \
        F0, __builtin_bit_cast(f16x8, p), acc, 0, 0, 0);                      \
    {                                                                         \
        float s0 = fmaxf(d[8],  CLAMPS), s1 = fmaxf(d[9],  CLAMPS);           \
        float s2 = fmaxf(d[10], CLAMPS), s3 = fmaxf(d[11], CLAMPS);           \
        float s4 = fmaxf(d[12], CLAMPS), s5 = fmaxf(d[13], CLAMPS);           \
        float w0 = __builtin_bit_cast(float,(__builtin_bit_cast(int,s0)<<15)+KBITS);\
        float w1 = __builtin_bit_cast(float,(__builtin_bit_cast(int,s1)<<15)+KBITS);\
        float w2 = __builtin_bit_cast(float,(__builtin_bit_cast(int,s2)<<15)+KBITS);\
        float w3 = __builtin_bit_cast(float,(__builtin_bit_cast(int,s3)<<15)+KBITS);\
        float w4 = __builtin_bit_cast(float,(__builtin_bit_cast(int,s4)<<15)+KBITS);\
        float w5 = __builtin_bit_cast(float,(__builtin_bit_cast(int,s5)<<15)+KBITS);\
        float s6 = fmaxf(d[14], CLAMPS), s7 = fmaxf(d[15], CLAMPS);           \
        float w6 = __builtin_bit_cast(float,(__builtin_bit_cast(int,s6)<<15)+KBITS);\
        float w7 = __builtin_bit_cast(float,(__builtin_bit_cast(int,s7)<<15)+KBITS);\
        p.x = pkrtz(w0, w1); p.y = pkrtz(w2, w3);                             \
        p.z = pkrtz(w4, w5); p.w = pkrtz(w6, w7);                             \
    }                                                                         \
    acc = __builtin_amdgcn_mfma_f32_32x32x16_f16(                             \
        F1, __builtin_bit_cast(f16x8, p), acc, 0, 0, 0);                      \
} while (0)

    // ---- preloop: tile 0 ----
    uint4 aw; unsigned hfx, hfy, hfz;
    LOADR(wbase + lq);
    MAKEA(aw, hfx, hfy, hfz);
    FWRITE(0, hfx, hfy, hfz);
    f32x16 d = __builtin_amdgcn_mfma_f32_32x32x16_f16(
        __builtin_bit_cast(f16x8, aw), Bf, zc, 0, 0, 0);

    // ---- 32 tiles, 2 per iteration (static LDS buf indices) ----
    for (int tt = 0; tt < 16; ++tt) {
        // even: consume tile 2tt (buf0), build tile 2tt+1 -> buf1
        LOADR(wbase + (2*tt + 1) * 32 + lq);       // issued early, used late
        EXPPV(0);
        MAKEA(aw, hfx, hfy, hfz);
        FWRITE(1, hfx, hfy, hfz);
        d = __builtin_amdgcn_mfma_f32_32x32x16_f16(
            __builtin_bit_cast(f16x8, aw), Bf, zc, 0, 0, 0);
        // odd: consume tile 2tt+1 (buf1), build tile 2tt+2 -> buf0
        LOADR(wbase + (2*tt + 2) * 32 + lq);       // clamped at the end
        EXPPV(1);
        MAKEA(aw, hfx, hfy, hfz);
        FWRITE(0, hfx, hfy, hfz);
        d = __builtin_amdgcn_mfma_f32_32x32x16_f16(
            __builtin_bit_cast(f16x8, aw), Bf, zc, 0, 0, 0);
    }
#undef LOADR
#undef MAKEA
#undef FWRITE
#undef EXPPV

    // ---- cross-wave reduce + normalize + write ----
    if (hi == 0) red[w][lq] = make_float4(acc[0], acc[1], acc[2], acc[3]);
    __syncthreads();
    if (t < 32) {
        float nx = 0.f, ny = 0.f, nz = 0.f, dn = 0.f;
#pragma unroll
        for (int ww = 0; ww < 8; ++ww) {
            float4 r = red[ww][t];
            nx += r.x; ny += r.y; nz += r.z; dn += r.w;
        }
        const float inv = 1.0f / dn;
        const int nq = nbase + t;
        out[b*3*N2S + 0*N2S + nq] = x2b[0*N2S+nq] - nx*inv;
        out[b*3*N2S + 1*N2S + nq] = x2b[1*N2S+nq] - ny*inv;
        out[b*3*N2S + 2*N2S + nq] = x2b[2*N2S+nq] - nz*inv;
    }
}

extern "C" void kernel_launch(void* const* d_in, const int* in_sizes, int n_in,
                              void* d_out, int out_size, void* d_ws, size_t ws_size,
                              hipStream_t stream) {
    const float* xyz1  = (const float*)d_in[0];
    const float* xyz2  = (const float*)d_in[1];
    const float* flow1 = (const float*)d_in[2];
    const void*  resol = d_in[3];
    float* out = (float*)d_out;
    (void)d_ws; (void)ws_size;    // workspace unused: single fused kernel

    pw2_fused<<<NQ / 32, BLK, 0, stream>>>(xyz1, xyz2, flow1, resol, out);
}

// Round 4
// 80.546 us; speedup vs baseline: 1.0690x; 1.0690x over previous
//
#include <hip/hip_runtime.h>

// PointWarping2 = flash-attention with head-dim 3:
//   flow2 = softmax(-d2/s^2) @ f1  (Schraudolph exp2, MAGIC-fold).
// R21: two-kernel structure (R19 was best measured; R20 fusion regressed).
// Changes vs R19:
//  (1) Score MFMA: 32x32x8_f16 with C = broadcast(MAGIC + qc) per lane.
//      C[reg][lane] depends only on col=lane&31 -> per-query constant is a
//      legal C operand. Frees qc from B, K drops 16->8, qc now exact f32.
//      A (per source, f16): k0-3 {yx,yx,yy,yy} (lanes<32),
//                           k4-7 {yz,yz,wh,wl} (lanes>=32), w=-c1|y|^2 hi/lo.
//      B (per query, f16):  k0-3 {Xh,Xl,Yh,Yl}, k4-7 {Zh,Zl,1,1}, X=2c1*qx.
//      => D = MAGIC - c1*d2 (same arg as R12/R19).
//  (2) 64 queries/block (2 B-frags + 2 acc per wave): same source-tile loads
//      feed 2x the MFMA/VALU work -> loads/VALU halved; 256 WGs (1 blk/CU).
//  (3) Depth-2 prefetch on srcA and fpk (~2 tiles ~ 300+ cyc lookahead).
// PV MFMA (32x32x16_f16) unchanged from R19/R20: D layout (col=lane&31=q,
// row=(reg&3)+8*(reg>>2)+4*hi=src) means cvt_pkrtz(w2j,w2j+1) IS the PV
// B-operand when flow values are stored in the permuted order
// {0-3,8-11 | 4-7,12-15} per 16-source group (done in pack -> fpk).
// acc regs 0-3 on lanes<32 = (nx,ny,nz,den) per query.

#define N1S  8192
#define N2S  8192
#define BATCH 2
#define NS   (BATCH * N1S)       // 16384 sources
#define NQ   (BATCH * N2S)       // 16384 queries
#define GA   (NS + 128)          // srcA records + guard
#define NF   (NS/2 + 64)         // fpk records + guard
#define BLK  512                 // 8 waves; each wave: 1024 sources = 32 tiles
#define QBQ  64                  // queries per block (2 cols of 32)
#define LOG2E 1.4426950408889634f
#define MAGIC 49152.0f           // 1.5*2^15
#define CLAMPS (MAGIC - 120.0f)
#define KBITS 1064990910         // (127<<23) - 362306: rel err +-3.04%
#define ONEH 0x3C00u             // f16(1.0)

typedef __attribute__((ext_vector_type(4)))  _Float16 f16x4;
typedef __attribute__((ext_vector_type(8)))  _Float16 f16x8;
typedef __attribute__((ext_vector_type(16))) float    f32x16;

__device__ __forceinline__ float read_scale(const void* p) {
    // resol_factor: 1-elem array; Python int -> int32, float -> fp32.
    int iv = *(const int*)p;
    if (iv > -(1 << 23) && iv < (1 << 23)) return (float)iv;
    return *(const float*)p;
}

__device__ __forceinline__ unsigned hb(float v) {        // f16 bits, RNE
    return (unsigned)__builtin_bit_cast(unsigned short, (_Float16)v);
}
__device__ __forceinline__ float h2f(unsigned b16) {     // f16 bits -> fp32
    return (float)__builtin_bit_cast(_Float16, (unsigned short)(b16 & 0xFFFFu));
}
__device__ __forceinline__ unsigned pkrtz(float a, float b) { // {f16 a, f16 b}
    return __builtin_bit_cast(unsigned, __builtin_amdgcn_cvt_pkrtz(a, b));
}

// ---- k1: build srcA (score A-operand) and fpk (PV A-operand, f16) ----
__global__ __launch_bounds__(256) void pw2_pack(
    const float* __restrict__ xyz1, const float* __restrict__ flow1,
    const void* __restrict__ resol, uint4* __restrict__ srcA,
    uint4* __restrict__ fpk)
{
    const int i = blockIdx.x * 256 + threadIdx.x;
    const float scale = read_scale(resol);
    const float c1 = LOG2E / (scale * scale);

    if (i < NS) {
        const int b = i >> 13, m = i & (N1S - 1);
        const float* x1b = xyz1  + b * 3 * N1S;
        const float* f1b = flow1 + b * 3 * N1S;
        float fx = f1b[0*N1S+m], fy = f1b[1*N1S+m], fz = f1b[2*N1S+m];
        float yx = x1b[0*N1S+m]+fx, yy = x1b[1*N1S+m]+fy, yz = x1b[2*N1S+m]+fz;
        float wq = -c1 * (yx*yx + yy*yy + yz*yz);   // fp32-exact, f16 hi/lo
        unsigned hx = hb(yx), hy = hb(yy), hz = hb(yz);
        unsigned wh = hb(wq), wl = hb(wq - h2f(wh));
        uint4 A;                      // halves: lanes<32 read .xy, >=32 .zw
        A.x = hx | (hx << 16);        // k0,k1 = yx,yx
        A.y = hy | (hy << 16);        // k2,k3 = yy,yy
        A.z = hz | (hz << 16);        // k4,k5 = yz,yz
        A.w = wh | (wl << 16);        // k6,k7 = wh,wl
        srcA[i] = A;
    }

    if (i < NS / 2) {
        // fpk record i: group g of 16 sources, half h, component c (c=3 -> 1).
        // k-order permutation per group: h=0 -> {0,1,2,3,8,9,10,11},
        //                                h=1 -> {4,5,6,7,12,13,14,15}.
        const int g = i >> 3, h = (i >> 2) & 1, c = i & 3;
        const int b = g >> 9, m0 = (g & 511) * 16;
        const float* f1c = flow1 + b * 3 * N1S + (c < 3 ? c : 0) * N1S;
        const int base = h * 4;
        unsigned e[8];
#pragma unroll
        for (int j = 0; j < 8; ++j) {
            int s = m0 + base + (j & 3) + (j >> 2) * 8;
            e[j] = (c == 3) ? ONEH : hb(f1c[s]);
        }
        uint4 F;
        F.x = e[0] | (e[1] << 16);
        F.y = e[2] | (e[3] << 16);
        F.z = e[4] | (e[5] << 16);
        F.w = e[6] | (e[7] << 16);
        fpk[i] = F;
    }
}

// ---- k2: MFMA main kernel, 64 queries/block ----
__global__ __launch_bounds__(BLK, 2) void pw2_main(
    const uint4* __restrict__ srcA, const uint4* __restrict__ fpk,
    const float* __restrict__ xyz2, const void* __restrict__ resol,
    float* __restrict__ out)
{
    __shared__ float4 red[8][QBQ];    // [wave][query] partial (nx,ny,nz,den)

    const int t  = threadIdx.x;
    const int w  = t >> 6, l = t & 63, lq = l & 31, hi = l >> 5;
    const int qblk  = blockIdx.x * QBQ;
    const int b     = qblk >> 13;
    const int nbase = qblk & (N2S - 1);

    const float scale = read_scale(resol);
    const float c1 = LOG2E / (scale * scale), twoC = 2.0f * c1;
    const float* x2b = xyz2 + b * 3 * N2S;

    // ---- per-lane query constants for 2 columns -> B frags + C consts ----
    uint2 bw0, bw1; float cc0, cc1;
    {
        const int n0 = nbase + lq;
        const float qx = x2b[n0], qy = x2b[N2S+n0], qz = x2b[2*N2S+n0];
        const float Xc = twoC*qx, Yc = twoC*qy, Zc = twoC*qz;
        const unsigned Xh = hb(Xc), Yh = hb(Yc), Zh = hb(Zc);
        const unsigned Xl = hb(Xc - h2f(Xh));
        const unsigned Yl = hb(Yc - h2f(Yh));
        const unsigned Zl = hb(Zc - h2f(Zh));
        bw0.x = hi ? (Zh | (Zl << 16)) : (Xh | (Xl << 16));
        bw0.y = hi ? (ONEH | (ONEH << 16)) : (Yh | (Yl << 16));
        cc0 = MAGIC - c1 * (qx*qx + qy*qy + qz*qz);   // exact f32 qc fold
    }
    {
        const int n1 = nbase + 32 + lq;
        const float qx = x2b[n1], qy = x2b[N2S+n1], qz = x2b[2*N2S+n1];
        const float Xc = twoC*qx, Yc = twoC*qy, Zc = twoC*qz;
        const unsigned Xh = hb(Xc), Yh = hb(Yc), Zh = hb(Zc);
        const unsigned Xl = hb(Xc - h2f(Xh));
        const unsigned Yl = hb(Yc - h2f(Yh));
        const unsigned Zl = hb(Zc - h2f(Zh));
        bw1.x = hi ? (Zh | (Zl << 16)) : (Xh | (Xl << 16));
        bw1.y = hi ? (ONEH | (ONEH << 16)) : (Yh | (Yl << 16));
        cc1 = MAGIC - c1 * (qx*qx + qy*qy + qz*qz);
    }
    const f16x4 Bf0 = __builtin_bit_cast(f16x4, bw0);
    const f16x4 Bf1 = __builtin_bit_cast(f16x4, bw1);

    f32x16 acc0, acc1, cq0, cq1;
#pragma unroll
    for (int k = 0; k < 16; ++k) {
        acc0[k] = 0.f; acc1[k] = 0.f; cq0[k] = cc0; cq1[k] = cc1;
    }

    // ---- source loop: 32 tiles x 32 sources; depth-2 guarded prefetch ----
    const uint2* a2 = (const uint2*)srcA;   // lane reads its 8B half-record
    int ia = (b * N1S + w * 1024 + lq) * 2 + hi;
    int ir = ((b * N1S + w * 1024) >> 4) * 8 + hi * 4 + (l & 3);

    uint2 s0 = a2[ia], s1 = a2[ia + 64];
    uint4 f00 = fpk[ir],      f10 = fpk[ir + 8];
    uint4 f01 = fpk[ir + 16], f11 = fpk[ir + 24];

    // d0 = col0 scores of tile 0
    f32x16 d0 = __builtin_amdgcn_mfma_f32_32x32x8f16(
        __builtin_bit_cast(f16x4, s0), Bf0, cq0, 0, 0, 0);

#define EXP8(D, O, P) do {                                                    \
    float e0 = fmaxf((D)[(O)+0], CLAMPS), e1 = fmaxf((D)[(O)+1], CLAMPS);     \
    float e2 = fmaxf((D)[(O)+2], CLAMPS), e3 = fmaxf((D)[(O)+3], CLAMPS);     \
    float e4 = fmaxf((D)[(O)+4], CLAMPS), e5 = fmaxf((D)[(O)+5], CLAMPS);     \
    float e6 = fmaxf((D)[(O)+6], CLAMPS), e7 = fmaxf((D)[(O)+7], CLAMPS);     \
    float g0 = __builtin_bit_cast(float,(__builtin_bit_cast(int,e0)<<15)+KBITS);\
    float g1 = __builtin_bit_cast(float,(__builtin_bit_cast(int,e1)<<15)+KBITS);\
    float g2 = __builtin_bit_cast(float,(__builtin_bit_cast(int,e2)<<15)+KBITS);\
    float g3 = __builtin_bit_cast(float,(__builtin_bit_cast(int,e3)<<15)+KBITS);\
    float g4 = __builtin_bit_cast(float,(__builtin_bit_cast(int,e4)<<15)+KBITS);\
    float g5 = __builtin_bit_cast(float,(__builtin_bit_cast(int,e5)<<15)+KBITS);\
    float g6 = __builtin_bit_cast(float,(__builtin_bit_cast(int,e6)<<15)+KBITS);\
    float g7 = __builtin_bit_cast(float,(__builtin_bit_cast(int,e7)<<15)+KBITS);\
    (P).x = pkrtz(g0, g1); (P).y = pkrtz(g2, g3);                             \
    (P).z = pkrtz(g4, g5); (P).w = pkrtz(g6, g7);                             \
} while (0)

#pragma unroll 2
    for (int tt = 0; tt < 32; ++tt) {
        // col1 scores of this tile (issued before consuming d0)
        f32x16 d1 = __builtin_amdgcn_mfma_f32_32x32x8f16(
            __builtin_bit_cast(f16x4, s0), Bf1, cq1, 0, 0, 0);

        // depth-2 prefetch (guard regions: always legal)
        const uint2 s2  = a2[ia + 128];
        const uint4 f02 = fpk[ir + 32];
        const uint4 f12 = fpk[ir + 40];

        // exp/PV for col0 (hides d1's latency)
        uint4 p;
        EXP8(d0, 0, p);
        acc0 = __builtin_amdgcn_mfma_f32_32x32x16_f16(
            __builtin_bit_cast(f16x8, f00), __builtin_bit_cast(f16x8, p),
            acc0, 0, 0, 0);
        EXP8(d0, 8, p);
        acc0 = __builtin_amdgcn_mfma_f32_32x32x16_f16(
            __builtin_bit_cast(f16x8, f10), __builtin_bit_cast(f16x8, p),
            acc0, 0, 0, 0);

        // next tile's col0 scores (hidden under col1's exp below;
        // tt==31 uses guard data, result never consumed)
        d0 = __builtin_amdgcn_mfma_f32_32x32x8f16(
            __builtin_bit_cast(f16x4, s1), Bf0, cq0, 0, 0, 0);

        // exp/PV for col1
        EXP8(d1, 0, p);
        acc1 = __builtin_amdgcn_mfma_f32_32x32x16_f16(
            __builtin_bit_cast(f16x8, f00), __builtin_bit_cast(f16x8, p),
            acc1, 0, 0, 0);
        EXP8(d1, 8, p);
        acc1 = __builtin_amdgcn_mfma_f32_32x32x16_f16(
            __builtin_bit_cast(f16x8, f10), __builtin_bit_cast(f16x8, p),
            acc1, 0, 0, 0);

        // rotate pipeline registers
        s0 = s1; s1 = s2;
        f00 = f01; f10 = f11; f01 = f02; f11 = f12;
        ia += 64; ir += 16;
    }
#undef EXP8

    // ---- cross-wave reduce + normalize + write ----
    if (hi == 0) {
        red[w][lq]      = make_float4(acc0[0], acc0[1], acc0[2], acc0[3]);
        red[w][32 + lq] = make_float4(acc1[0], acc1[1], acc1[2], acc1[3]);
    }
    __syncthreads();
    if (t < QBQ) {
        float nx = 0.f, ny = 0.f, nz = 0.f, dn = 0.f;
#pragma unroll
        for (int ww = 0; ww < 8; ++ww) {
            float4 r = red[ww][t];
            nx += r.x; ny += r.y; nz += r.z; dn += r.w;
        }
        const float inv = 1.0f / dn;
        const int nq = nbase + t;
        out[b*3*N2S + 0*N2S + nq] = x2b[0*N2S+nq] - nx * inv;
        out[b*3*N2S + 1*N2S + nq] = x2b[1*N2S+nq] - ny * inv;
        out[b*3*N2S + 2*N2S + nq] = x2b[2*N2S+nq] - nz * inv;
    }
}

extern "C" void kernel_launch(void* const* d_in, const int* in_sizes, int n_in,
                              void* d_out, int out_size, void* d_ws, size_t ws_size,
                              hipStream_t stream) {
    const float* xyz1  = (const float*)d_in[0];
    const float* xyz2  = (const float*)d_in[1];
    const float* flow1 = (const float*)d_in[2];
    const void*  resol = d_in[3];
    float* out = (float*)d_out;

    uint4* srcA = (uint4*)d_ws;        // GA records
    uint4* fpk  = srcA + GA;           // NF records; total ~400 KB

    pw2_pack<<<NS / 256, 256, 0, stream>>>(xyz1, flow1, resol, srcA, fpk);
    pw2_main<<<NQ / QBQ, BLK, 0, stream>>>(srcA, fpk, xyz2, resol, out);
}

// Round 6
// 73.938 us; speedup vs baseline: 1.1645x; 1.0894x over previous
//
#include <hip/hip_runtime.h>

// PointWarping2 = flash-attention with head-dim 3:
//   flow2 = softmax(-d2/s^2) @ f1  (Schraudolph exp2 in f16-bit domain).
// R23 = R22 with compile fix + corrected magic:
//  - cvt_pkrtz returns __fp16 ext_vector(2) -> hp2 typedef (was _Float16).
//  - WADJ re-derived exactly: bits16(w) = (bits16(s)<<4 mod 2^16) + C,
//    anchor s=30 -> w=1.0 (0x3C00): C_base = 0x4400; Schraudolph mid-corr
//    -44 (f32's 362306/2^23*1024) -> WADJ = 0x43D4. Per-half v_pk_add_u16
//    is REQUIRED (low half overflows 16 bits; no cross-half carry allowed).
// R22 design (untested until now): occupancy 2->4 waves/SIMD. BLK=1024
// (16 waves), grid 256 = 1 blk/CU, each wave 512 sources = 16 tiles;
// __launch_bounds__(1024,4) caps VGPR 128. To fit: qc in score-B k-slots
// (coords single-f16, C = shared zero vector); packed-f16 Schraudolph:
// s = 30 + log2(w) in [16,32) where f16 bits are affine in value:
//   per pair: cvt_pkrtz -> v_pk_max_f16(16) -> pk_lshl(4) -> pk_add(0x43D4)
// -- 4 VALU/pair, result IS the PV B-word.
//
// Score MFMA 32x32x8_f16: D[src][q] = A.B + 0
//   A (per source): k0-3 {yx,yy,yz,1} (lanes<32), k4-7 {1,wh,wl,0}
//     (w = -c1*|y|^2 fp32 -> f16 hi/lo; coords single f16)
//   B (per query):  k0-3 {X,Y,Z,qch}, k4-7 {qcl,1,1,0}
//     (X = 2c1*qx f16; qc = 30 - c1*|q|^2 f16 hi/lo)
//   => D = 30 - c1*d2 = 30 + log2(weight).
// PV MFMA 32x32x16_f16 unchanged: D layout (col=lane&31=q,
// row=(reg&3)+8*(reg>>2)+4*hi=src) means the packed weight words ARE the
// PV B-operand when flow values are stored permuted {0-3,8-11 | 4-7,12-15}
// per 16-source group (pack kernel -> fpk).
// acc regs 0-3 on lanes<32 = (nx,ny,nz,den) per query.

#define N1S  8192
#define N2S  8192
#define BATCH 2
#define NS   (BATCH * N1S)       // 16384 sources
#define NQ   (BATCH * N2S)       // 16384 queries
#define GA   (NS + 128)          // srcA records + guard
#define NF   (NS/2 + 64)         // fpk records + guard
#define BLK  1024                // 16 waves; each wave: 512 sources = 16 tiles
#define QBQ  64                  // queries per block (2 cols of 32)
#define LOG2E 1.4426950408889634f
#define BIAS 30.0f               // s = BIAS + log2(w); s in [16, ~30.1]
#define ONEH 0x3C00u             // f16(1.0)
#define WADJ 0x43D4u             // 0x4400 base - 44 Schraudolph mid-corr

typedef __attribute__((ext_vector_type(2)))  __fp16         hp2;
typedef __attribute__((ext_vector_type(2)))  unsigned short u16x2;
typedef __attribute__((ext_vector_type(4)))  _Float16 f16x4;
typedef __attribute__((ext_vector_type(8)))  _Float16 f16x8;
typedef __attribute__((ext_vector_type(16))) float    f32x16;

__device__ __forceinline__ float read_scale(const void* p) {
    // resol_factor: 1-elem array; Python int -> int32, float -> fp32.
    int iv = *(const int*)p;
    if (iv > -(1 << 23) && iv < (1 << 23)) return (float)iv;
    return *(const float*)p;
}

__device__ __forceinline__ unsigned hb(float v) {        // f16 bits, RNE
    return (unsigned)__builtin_bit_cast(unsigned short, (_Float16)v);
}
__device__ __forceinline__ float h2f(unsigned b16) {     // f16 bits -> fp32
    return (float)__builtin_bit_cast(_Float16, (unsigned short)(b16 & 0xFFFFu));
}

// two Schraudolph-f16 weights from two f32 scores: one packed PV B-word
__device__ __forceinline__ unsigned wpair(float a, float b) {
    hp2 s = __builtin_amdgcn_cvt_pkrtz(a, b);            // v_cvt_pkrtz_f16_f32
    const hp2 cl = {(__fp16)16.0f, (__fp16)16.0f};
    s = __builtin_elementwise_max(s, cl);                // v_pk_max_f16
    u16x2 u = __builtin_bit_cast(u16x2, s);
    u = u << 4;                                          // v_pk_lshlrev_b16
    u = u + (u16x2){(unsigned short)WADJ, (unsigned short)WADJ}; // v_pk_add_u16
    return __builtin_bit_cast(unsigned, u);
}

// ---- k1: build srcA (score A-operand) and fpk (PV A-operand, f16) ----
__global__ __launch_bounds__(256) void pw2_pack(
    const float* __restrict__ xyz1, const float* __restrict__ flow1,
    const void* __restrict__ resol, uint4* __restrict__ srcA,
    uint4* __restrict__ fpk)
{
    const int i = blockIdx.x * 256 + threadIdx.x;
    const float scale = read_scale(resol);
    const float c1 = LOG2E / (scale * scale);

    if (i < NS) {
        const int b = i >> 13, m = i & (N1S - 1);
        const float* x1b = xyz1  + b * 3 * N1S;
        const float* f1b = flow1 + b * 3 * N1S;
        float fx = f1b[0*N1S+m], fy = f1b[1*N1S+m], fz = f1b[2*N1S+m];
        float yx = x1b[0*N1S+m]+fx, yy = x1b[1*N1S+m]+fy, yz = x1b[2*N1S+m]+fz;
        float wq = -c1 * (yx*yx + yy*yy + yz*yz);   // fp32-exact, f16 hi/lo
        unsigned hx = hb(yx), hy = hb(yy), hz = hb(yz);
        unsigned wh = hb(wq), wl = hb(wq - h2f(wh));
        uint4 A;                      // halves: lanes<32 read .xy, >=32 .zw
        A.x = hx | (hy << 16);        // k0,k1 = yx,yy
        A.y = hz | (ONEH << 16);      // k2,k3 = yz,1
        A.z = ONEH | (wh << 16);      // k4,k5 = 1,wh
        A.w = wl;                     // k6,k7 = wl,0
        srcA[i] = A;
    }

    if (i < NS / 2) {
        // fpk record i: group g of 16 sources, half h, component c (c=3 -> 1).
        // k-order permutation per group: h=0 -> {0,1,2,3,8,9,10,11},
        //                                h=1 -> {4,5,6,7,12,13,14,15}.
        const int g = i >> 3, h = (i >> 2) & 1, c = i & 3;
        const int b = g >> 9, m0 = (g & 511) * 16;
        const float* f1c = flow1 + b * 3 * N1S + (c < 3 ? c : 0) * N1S;
        const int base = h * 4;
        unsigned e[8];
#pragma unroll
        for (int j = 0; j < 8; ++j) {
            int s = m0 + base + (j & 3) + (j >> 2) * 8;
            e[j] = (c == 3) ? ONEH : hb(f1c[s]);
        }
        uint4 F;
        F.x = e[0] | (e[1] << 16);
        F.y = e[2] | (e[3] << 16);
        F.z = e[4] | (e[5] << 16);
        F.w = e[6] | (e[7] << 16);
        fpk[i] = F;
    }
}

// ---- k2: MFMA main kernel, 64 queries/block, 16 waves ----
__global__ __launch_bounds__(BLK, 4) void pw2_main(
    const uint4* __restrict__ srcA, const uint4* __restrict__ fpk,
    const float* __restrict__ xyz2, const void* __restrict__ resol,
    float* __restrict__ out)
{
    __shared__ float4 red[16][QBQ];   // [wave][query] partial (nx,ny,nz,den)

    const int t  = threadIdx.x;
    const int w  = t >> 6, l = t & 63, lq = l & 31, hi = l >> 5;
    const int qblk  = blockIdx.x * QBQ;
    const int b     = qblk >> 13;
    const int nbase = qblk & (N2S - 1);

    const float scale = read_scale(resol);
    const float c1 = LOG2E / (scale * scale), twoC = 2.0f * c1;
    const float* x2b = xyz2 + b * 3 * N2S;

    // ---- per-lane query constants for 2 columns -> B frags ----
    uint2 bw0, bw1;
#pragma unroll
    for (int cc = 0; cc < 2; ++cc) {
        const int n0 = nbase + 32 * cc + lq;
        const float qx = x2b[n0], qy = x2b[N2S+n0], qz = x2b[2*N2S+n0];
        const unsigned Xh = hb(twoC*qx), Yh = hb(twoC*qy), Zh = hb(twoC*qz);
        const float qc = BIAS - c1 * (qx*qx + qy*qy + qz*qz);
        const unsigned Qh = hb(qc), Ql = hb(qc - h2f(Qh));
        uint2 bwv;
        bwv.x = hi ? (Ql | (ONEH << 16)) : (Xh | (Yh << 16)); // k4,k5 | k0,k1
        bwv.y = hi ? ONEH                : (Zh | (Qh << 16)); // k6,k7 | k2,k3
        if (cc == 0) bw0 = bwv; else bw1 = bwv;
    }
    const f16x4 Bf0 = __builtin_bit_cast(f16x4, bw0);
    const f16x4 Bf1 = __builtin_bit_cast(f16x4, bw1);

    f32x16 acc0, acc1, zc;
#pragma unroll
    for (int k = 0; k < 16; ++k) { acc0[k] = 0.f; acc1[k] = 0.f; zc[k] = 0.f; }

    // ---- source loop: 16 tiles x 32 sources; depth-1 guarded prefetch ----
    const uint2* a2 = (const uint2*)srcA;   // lane reads its 8B half-record
    int ia = (b * N1S + w * 512 + lq) * 2 + hi;
    int ir = ((b * N1S + w * 512) >> 4) * 8 + hi * 4 + (l & 3);

    uint2 s0 = a2[ia];
    uint4 f0 = fpk[ir], f1 = fpk[ir + 8];

#pragma unroll 2
    for (int tt = 0; tt < 16; ++tt) {
        // prefetch next tile (guard regions: always legal)
        const uint2 s0n = a2[ia + 64];
        const uint4 f0n = fpk[ir + 16];
        const uint4 f1n = fpk[ir + 24];

        const f32x16 d0 = __builtin_amdgcn_mfma_f32_32x32x8f16(
            __builtin_bit_cast(f16x4, s0), Bf0, zc, 0, 0, 0);
        const f32x16 d1 = __builtin_amdgcn_mfma_f32_32x32x8f16(
            __builtin_bit_cast(f16x4, s0), Bf1, zc, 0, 0, 0);

        uint4 p;
        p.x = wpair(d0[0],  d0[1]);  p.y = wpair(d0[2],  d0[3]);
        p.z = wpair(d0[4],  d0[5]);  p.w = wpair(d0[6],  d0[7]);
        acc0 = __builtin_amdgcn_mfma_f32_32x32x16_f16(
            __builtin_bit_cast(f16x8, f0), __builtin_bit_cast(f16x8, p),
            acc0, 0, 0, 0);
        p.x = wpair(d0[8],  d0[9]);  p.y = wpair(d0[10], d0[11]);
        p.z = wpair(d0[12], d0[13]); p.w = wpair(d0[14], d0[15]);
        acc0 = __builtin_amdgcn_mfma_f32_32x32x16_f16(
            __builtin_bit_cast(f16x8, f1), __builtin_bit_cast(f16x8, p),
            acc0, 0, 0, 0);

        p.x = wpair(d1[0],  d1[1]);  p.y = wpair(d1[2],  d1[3]);
        p.z = wpair(d1[4],  d1[5]);  p.w = wpair(d1[6],  d1[7]);
        acc1 = __builtin_amdgcn_mfma_f32_32x32x16_f16(
            __builtin_bit_cast(f16x8, f0), __builtin_bit_cast(f16x8, p),
            acc1, 0, 0, 0);
        p.x = wpair(d1[8],  d1[9]);  p.y = wpair(d1[10], d1[11]);
        p.z = wpair(d1[12], d1[13]); p.w = wpair(d1[14], d1[15]);
        acc1 = __builtin_amdgcn_mfma_f32_32x32x16_f16(
            __builtin_bit_cast(f16x8, f1), __builtin_bit_cast(f16x8, p),
            acc1, 0, 0, 0);

        s0 = s0n; f0 = f0n; f1 = f1n;
        ia += 64; ir += 16;
    }

    // ---- cross-wave reduce + normalize + write ----
    if (hi == 0) {
        red[w][lq]      = make_float4(acc0[0], acc0[1], acc0[2], acc0[3]);
        red[w][32 + lq] = make_float4(acc1[0], acc1[1], acc1[2], acc1[3]);
    }
    __syncthreads();
    if (t < QBQ) {
        float nx = 0.f, ny = 0.f, nz = 0.f, dn = 0.f;
#pragma unroll
        for (int ww = 0; ww < 16; ++ww) {
            float4 r = red[ww][t];
            nx += r.x; ny += r.y; nz += r.z; dn += r.w;
        }
        const float inv = 1.0f / dn;
        const int nq = nbase + t;
        out[b*3*N2S + 0*N2S + nq] = x2b[0*N2S+nq] - nx * inv;
        out[b*3*N2S + 1*N2S + nq] = x2b[1*N2S+nq] - ny * inv;
        out[b*3*N2S + 2*N2S + nq] = x2b[2*N2S+nq] - nz * inv;
    }
}

extern "C" void kernel_launch(void* const* d_in, const int* in_sizes, int n_in,
                              void* d_out, int out_size, void* d_ws, size_t ws_size,
                              hipStream_t stream) {
    const float* xyz1  = (const float*)d_in[0];
    const float* xyz2  = (const float*)d_in[1];
    const float* flow1 = (const float*)d_in[2];
    const void*  resol = d_in[3];
    float* out = (float*)d_out;

    uint4* srcA = (uint4*)d_ws;        // GA records
    uint4* fpk  = srcA + GA;           // NF records; total ~400 KB

    pw2_pack<<<NS / 256, 256, 0, stream>>>(xyz1, flow1, resol, srcA, fpk);
    pw2_main<<<NQ / QBQ, BLK, 0, stream>>>(srcA, fpk, xyz2, resol, out);
}